// Round 18
// baseline (506.267 us; speedup 1.0000x reference)
//
#include <hip/hip_runtime.h>

#define N_NODES 10000
#define N_EDGES 320000
#define NODE_DIM 128
#define EDGE_DIM 16
#define HIDDEN 256
#define N_OUT 8
#define N_GRAPHS 64
#define LOG2E 1.4426950408889634f

typedef float f32x4 __attribute__((ext_vector_type(4)));
typedef short bf16x8 __attribute__((ext_vector_type(8)));
typedef _Float16 half2_t __attribute__((ext_vector_type(2)));

__device__ __forceinline__ unsigned short f2bf(float f) {
  unsigned int u = __float_as_uint(f);
  unsigned int r = (u + 0x7fff + ((u >> 16) & 1)) >> 16;
  return (unsigned short)r;
}

__device__ __forceinline__ float bf2f(unsigned short u) {
  return __uint_as_float((unsigned int)u << 16);
}

__device__ __forceinline__ unsigned int packh2(float a, float b) {
  half2_t h;
  h.x = (_Float16)a;
  h.y = (_Float16)b;
  return __builtin_bit_cast(unsigned int, h);
}

__device__ __forceinline__ half2_t h2(unsigned int u) {
  return __builtin_bit_cast(half2_t, u);
}

// ---------------- CSR build ----------------
__global__ void hist_kernel(const int* __restrict__ dst, int* __restrict__ counts, int E) {
  int e = blockIdx.x * blockDim.x + threadIdx.x;
  if (e < E) atomicAdd(&counts[dst[e]], 1);
}

__global__ void scan_kernel(const int* __restrict__ counts, int* __restrict__ offs,
                            int* __restrict__ cursor, int n) {
  __shared__ int part[256];
  int t = threadIdx.x;
  const int chunk = (n + 255) / 256;
  int base = t * chunk;
  int s = 0;
  for (int j = 0; j < chunk; ++j) { int i = base + j; if (i < n) s += counts[i]; }
  part[t] = s;
  __syncthreads();
  for (int off = 1; off < 256; off <<= 1) {
    int v = (t >= off) ? part[t - off] : 0;
    __syncthreads();
    part[t] += v;
    __syncthreads();
  }
  int run = (t == 0) ? 0 : part[t - 1];
  for (int j = 0; j < chunk; ++j) {
    int i = base + j;
    if (i < n) { offs[i] = run; cursor[i] = run; run += counts[i]; }
  }
  if (t == 255) offs[n] = run;
}

// scatter edges into CSR order; attr packed as 8x half2 per edge
__global__ void scatter_kernel(const int* __restrict__ ei, const float* __restrict__ eattr,
                               int* __restrict__ cursor, int* __restrict__ csr_src,
                               unsigned int* __restrict__ attr16, int E) {
  int e = blockIdx.x * blockDim.x + threadIdx.x;
  if (e >= E) return;
  int s = ei[e];
  int d = ei[E + e];
  int slot = atomicAdd(&cursor[d], 1);
  csr_src[slot] = s;
  const float4* in = (const float4*)(eattr + (size_t)e * 16);
  float4 v0 = in[0], v1 = in[1], v2 = in[2], v3 = in[3];
  uint4 o0, o1;
  o0.x = packh2(v0.x, v0.y); o0.y = packh2(v0.z, v0.w);
  o0.z = packh2(v1.x, v1.y); o0.w = packh2(v1.z, v1.w);
  o1.x = packh2(v2.x, v2.y); o1.y = packh2(v2.z, v2.w);
  o1.z = packh2(v3.x, v3.y); o1.w = packh2(v3.z, v3.w);
  uint4* outp = (uint4*)(attr16 + (size_t)slot * 8);
  outp[0] = o0; outp[1] = o1;
}

// ---------------- degree sort, single block, LDS histogram + cursors ----------------
__global__ __launch_bounds__(256) void degsort_kernel(const int* __restrict__ offs,
                                                      int* __restrict__ order, int n) {
  __shared__ int bins[512];
  __shared__ int curs[512];
  const int t = threadIdx.x;
  bins[t] = 0;
  bins[t + 256] = 0;
  __syncthreads();
  for (int i = t; i < n; i += 256) {
    int d = offs[i + 1] - offs[i];
    if (d > 511) d = 511;
    atomicAdd(&bins[d], 1);
  }
  __syncthreads();
  if (t == 0) {
    int run = 0;
    for (int d = 511; d >= 0; --d) { curs[d] = run; run += bins[d]; }
  }
  __syncthreads();
  for (int i = t; i < n; i += 256) {
    int d = offs[i + 1] - offs[i];
    if (d > 511) d = 511;
    int pos = atomicAdd(&curs[d], 1);
    order[pos] = i;
  }
}

// ---------------- weight / activation conversion (all layers upfront) ----------------
__global__ void cvt_w_all(const float* __restrict__ Wl1, const float* __restrict__ Wr1,
                          const float* __restrict__ Wls, const float* __restrict__ Wrs,
                          unsigned short* __restrict__ WTall) {
  const int layer = blockIdx.y;
  const int K = (layer == 0) ? NODE_DIM : HIDDEN;
  int idx = blockIdx.x * 256 + threadIdx.x;
  if (idx >= 512 * K) return;
  int n = idx / K, k = idx - n * K;
  const float* Wl = (layer == 0) ? Wl1 : Wls + (size_t)(layer - 1) * HIDDEN * HIDDEN;
  const float* Wr = (layer == 0) ? Wr1 : Wrs + (size_t)(layer - 1) * HIDDEN * HIDDEN;
  float v = (n < 256) ? Wl[(size_t)k * 256 + n] : Wr[(size_t)k * 256 + (n - 256)];
  WTall[(size_t)layer * 512 * 256 + idx] = f2bf(v);
}

// WeP[layer][dp][col] = pack(We[2dp][col], We[2dp+1][col]) as half2
__global__ void cvt_wep(const float* __restrict__ We1, const float* __restrict__ Wes,
                        unsigned int* __restrict__ WePall) {
  int idx = blockIdx.x * 256 + threadIdx.x;
  if (idx >= 5 * 8 * 256) return;
  int layer = idx >> 11;
  int rem = idx & 2047;
  int dp = rem >> 8, col = rem & 255;
  const float* W = (layer == 0) ? We1 : Wes + (size_t)(layer - 1) * EDGE_DIM * HIDDEN;
  WePall[idx] = packh2(W[(2 * dp) * HIDDEN + col], W[(2 * dp + 1) * HIDDEN + col]);
}

__global__ void cvt_x(const float* __restrict__ X, unsigned short* __restrict__ XB, int total4) {
  int idx = blockIdx.x * 256 + threadIdx.x;
  if (idx >= total4) return;
  float4 v = *(const float4*)(X + (size_t)idx * 4);
  ushort4 o;
  o.x = f2bf(v.x); o.y = f2bf(v.y); o.z = f2bf(v.z); o.w = f2bf(v.w);
  *(ushort4*)(XB + (size_t)idx * 4) = o;
}

// ---------------- MFMA node GEMM: 64-row tile (32KB LDS), swizzled A, bf16 output ----------------
__global__ __launch_bounds__(256) void gemm_mfma(
    const unsigned short* __restrict__ A,   // [M][K] bf16 row-major
    const unsigned short* __restrict__ WT,  // [512][K] bf16 (output-col major)
    const float* __restrict__ bl, const float* __restrict__ br,
    unsigned short* __restrict__ C, int M, int K) {
  __shared__ unsigned short Atile[64 * 256];  // 32KB
  const int t = threadIdx.x;
  const int wv = t >> 6;
  const int l = t & 63;
  const int bm = blockIdx.x * 64;
  const int bn = blockIdx.y * 128;
  const int CPR = K >> 3;
  const int nchunks = 64 * CPR;

  for (int p = t; p < nchunks; p += 256) {
    const int r = p / CPR;
    const int c = p - r * CPR;
    int gr = bm + r; if (gr >= M) gr = M - 1;
    const uint4 v = *(const uint4*)(A + (size_t)gr * K + c * 8);
    const int eff = c ^ (r & 7);
    *(uint4*)((char*)Atile + ((size_t)r * CPR + eff) * 16) = v;
  }
  __syncthreads();

  const int col0 = bn + wv * 32 + (l & 15);
  const int col1 = col0 + 16;
  const int kg = l >> 4;
  f32x4 acc[4][2];
#pragma unroll
  for (int mt = 0; mt < 4; ++mt) {
    acc[mt][0] = (f32x4){0.f, 0.f, 0.f, 0.f};
    acc[mt][1] = (f32x4){0.f, 0.f, 0.f, 0.f};
  }
  const int steps = K >> 5;
  for (int ks = 0; ks < steps; ++ks) {
    const bf16x8 bf0 = *(const bf16x8*)(WT + (size_t)col0 * K + ks * 32 + kg * 8);
    const bf16x8 bf1 = *(const bf16x8*)(WT + (size_t)col1 * K + ks * 32 + kg * 8);
#pragma unroll
    for (int mt = 0; mt < 4; ++mt) {
      const int row = mt * 16 + (l & 15);
      const int eff = (ks * 4 + kg) ^ (row & 7);
      const bf16x8 af = *(const bf16x8*)((const char*)Atile + ((size_t)row * CPR + eff) * 16);
      acc[mt][0] = __builtin_amdgcn_mfma_f32_16x16x32_bf16(af, bf0, acc[mt][0], 0, 0, 0);
      acc[mt][1] = __builtin_amdgcn_mfma_f32_16x16x32_bf16(af, bf1, acc[mt][1], 0, 0, 0);
    }
  }
  const float bias0 = (col0 < 256) ? bl[col0] : br[col0 - 256];
  const float bias1 = (col1 < 256) ? bl[col1] : br[col1 - 256];
#pragma unroll
  for (int mt = 0; mt < 4; ++mt) {
#pragma unroll
    for (int j = 0; j < 4; ++j) {
      int row = bm + mt * 16 + (l >> 4) * 4 + j;
      if (row < M) {
        C[(size_t)row * 512 + col0] = f2bf(acc[mt][0][j] + bias0);
        C[(size_t)row * 512 + col1] = f2bf(acc[mt][1][j] + bias1);
      }
    }
  }
}

// ---------------- fused edge scoring + segment softmax + aggregate + BN + act ----------------
// R16 structure; edge attr hoisted to 8 uint4 VMEM broadcast loads per iteration
// (issued alongside the xl gathers) so the fdot2 dp-loop is pure VALU with no
// mid-loop SMEM waits.
__global__ __launch_bounds__(256, 4) void edge_gat(
    const unsigned short* __restrict__ xlr,
    const int* __restrict__ offs, const int* __restrict__ csr_src,
    const unsigned int* __restrict__ attr16,
    const unsigned int* __restrict__ WeP, const float* __restrict__ att,
    const float* __restrict__ bconv,
    const float* __restrict__ gamma, const float* __restrict__ beta,
    const float* __restrict__ mean, const float* __restrict__ var,
    const int* __restrict__ order,
    unsigned short* __restrict__ hbf, int relu_last) {
  const int t = threadIdx.x;
  const int w = t >> 6;
  const int l = t & 63;
  const int h4 = l << 2;
  const int iu = __builtin_amdgcn_readfirstlane(order[blockIdx.x * 4 + w]);

  float4 att4 = *(const float4*)(att + h4);
  att4.x *= LOG2E; att4.y *= LOG2E; att4.z *= LOG2E; att4.w *= LOG2E;
  const ushort4 xru = *(const ushort4*)(xlr + (size_t)iu * 512 + HIDDEN + h4);
  const float4 xr4 = {bf2f(xru.x), bf2f(xru.y), bf2f(xru.z), bf2f(xru.w)};

  const int rs = __builtin_amdgcn_readfirstlane(offs[iu]);
  const int re = __builtin_amdgcn_readfirstlane(offs[iu + 1]);

  float mrun = -1e30f, den = 0.f;
  float4 acc = make_float4(0.f, 0.f, 0.f, 0.f);

  for (int e = rs; e < re; e += 4) {
    const int e0 = e;
    const int e1 = (e + 1 < re) ? e + 1 : e;
    const int e2 = (e + 2 < re) ? e + 2 : e;
    const int e3 = (e + 3 < re) ? e + 3 : e;
    const int s0 = __builtin_amdgcn_readfirstlane(csr_src[e0]);
    const int s1 = __builtin_amdgcn_readfirstlane(csr_src[e1]);
    const int s2 = __builtin_amdgcn_readfirstlane(csr_src[e2]);
    const int s3 = __builtin_amdgcn_readfirstlane(csr_src[e3]);
    // xl gathers + attr broadcast loads all issued up front (one vmcnt domain)
    const ushort4 xu0 = *(const ushort4*)(xlr + (size_t)s0 * 512 + h4);
    const ushort4 xu1 = *(const ushort4*)(xlr + (size_t)s1 * 512 + h4);
    const ushort4 xu2 = *(const ushort4*)(xlr + (size_t)s2 * 512 + h4);
    const ushort4 xu3 = *(const ushort4*)(xlr + (size_t)s3 * 512 + h4);
    const uint4 A0a = *(const uint4*)(attr16 + (size_t)e0 * 8);
    const uint4 A0b = *(const uint4*)(attr16 + (size_t)e0 * 8 + 4);
    const uint4 A1a = *(const uint4*)(attr16 + (size_t)e1 * 8);
    const uint4 A1b = *(const uint4*)(attr16 + (size_t)e1 * 8 + 4);
    const uint4 A2a = *(const uint4*)(attr16 + (size_t)e2 * 8);
    const uint4 A2b = *(const uint4*)(attr16 + (size_t)e2 * 8 + 4);
    const uint4 A3a = *(const uint4*)(attr16 + (size_t)e3 * 8);
    const uint4 A3b = *(const uint4*)(attr16 + (size_t)e3 * 8 + 4);
    const float4 xl0 = {bf2f(xu0.x), bf2f(xu0.y), bf2f(xu0.z), bf2f(xu0.w)};
    const float4 xl1 = {bf2f(xu1.x), bf2f(xu1.y), bf2f(xu1.z), bf2f(xu1.w)};
    const float4 xl2 = {bf2f(xu2.x), bf2f(xu2.y), bf2f(xu2.z), bf2f(xu2.w)};
    const float4 xl3 = {bf2f(xu3.x), bf2f(xu3.y), bf2f(xu3.z), bf2f(xu3.w)};

    float z0x = xr4.x, z0y = xr4.y, z0z = xr4.z, z0w = xr4.w;
    float z1x = xr4.x, z1y = xr4.y, z1z = xr4.z, z1w = xr4.w;
    float z2x = xr4.x, z2y = xr4.y, z2z = xr4.z, z2w = xr4.w;
    float z3x = xr4.x, z3y = xr4.y, z3z = xr4.z, z3w = xr4.w;

    const unsigned int a0c[8] = {A0a.x, A0a.y, A0a.z, A0a.w, A0b.x, A0b.y, A0b.z, A0b.w};
    const unsigned int a1c[8] = {A1a.x, A1a.y, A1a.z, A1a.w, A1b.x, A1b.y, A1b.z, A1b.w};
    const unsigned int a2c[8] = {A2a.x, A2a.y, A2a.z, A2a.w, A2b.x, A2b.y, A2b.z, A2b.w};
    const unsigned int a3c[8] = {A3a.x, A3a.y, A3a.z, A3a.w, A3b.x, A3b.y, A3b.z, A3b.w};

#pragma unroll
    for (int dp = 0; dp < 8; ++dp) {
      const uint4 wb = *(const uint4*)(WeP + dp * HIDDEN + h4);
      const half2_t wx = h2(wb.x), wy = h2(wb.y), wz = h2(wb.z), ww = h2(wb.w);
      const half2_t a0 = h2(a0c[dp]);
      const half2_t a1 = h2(a1c[dp]);
      const half2_t a2 = h2(a2c[dp]);
      const half2_t a3 = h2(a3c[dp]);
      z0x = __builtin_amdgcn_fdot2(a0, wx, z0x, false);
      z0y = __builtin_amdgcn_fdot2(a0, wy, z0y, false);
      z0z = __builtin_amdgcn_fdot2(a0, wz, z0z, false);
      z0w = __builtin_amdgcn_fdot2(a0, ww, z0w, false);
      z1x = __builtin_amdgcn_fdot2(a1, wx, z1x, false);
      z1y = __builtin_amdgcn_fdot2(a1, wy, z1y, false);
      z1z = __builtin_amdgcn_fdot2(a1, wz, z1z, false);
      z1w = __builtin_amdgcn_fdot2(a1, ww, z1w, false);
      z2x = __builtin_amdgcn_fdot2(a2, wx, z2x, false);
      z2y = __builtin_amdgcn_fdot2(a2, wy, z2y, false);
      z2z = __builtin_amdgcn_fdot2(a2, wz, z2z, false);
      z2w = __builtin_amdgcn_fdot2(a2, ww, z2w, false);
      z3x = __builtin_amdgcn_fdot2(a3, wx, z3x, false);
      z3y = __builtin_amdgcn_fdot2(a3, wy, z3y, false);
      z3z = __builtin_amdgcn_fdot2(a3, wz, z3z, false);
      z3w = __builtin_amdgcn_fdot2(a3, ww, z3w, false);
    }

    float p0, p1, p2, p3;
    {
      float zx, zy, zz, zw;
      zx = z0x + xl0.x; zy = z0y + xl0.y; zz = z0z + xl0.z; zw = z0w + xl0.w;
      zx = fmaxf(zx, 0.2f * zx); zy = fmaxf(zy, 0.2f * zy);
      zz = fmaxf(zz, 0.2f * zz); zw = fmaxf(zw, 0.2f * zw);
      p0 = att4.x * zx; p0 = fmaf(att4.y, zy, p0); p0 = fmaf(att4.z, zz, p0); p0 = fmaf(att4.w, zw, p0);
      zx = z1x + xl1.x; zy = z1y + xl1.y; zz = z1z + xl1.z; zw = z1w + xl1.w;
      zx = fmaxf(zx, 0.2f * zx); zy = fmaxf(zy, 0.2f * zy);
      zz = fmaxf(zz, 0.2f * zz); zw = fmaxf(zw, 0.2f * zw);
      p1 = att4.x * zx; p1 = fmaf(att4.y, zy, p1); p1 = fmaf(att4.z, zz, p1); p1 = fmaf(att4.w, zw, p1);
      zx = z2x + xl2.x; zy = z2y + xl2.y; zz = z2z + xl2.z; zw = z2w + xl2.w;
      zx = fmaxf(zx, 0.2f * zx); zy = fmaxf(zy, 0.2f * zy);
      zz = fmaxf(zz, 0.2f * zz); zw = fmaxf(zw, 0.2f * zw);
      p2 = att4.x * zx; p2 = fmaf(att4.y, zy, p2); p2 = fmaf(att4.z, zz, p2); p2 = fmaf(att4.w, zw, p2);
      zx = z3x + xl3.x; zy = z3y + xl3.y; zz = z3z + xl3.z; zw = z3w + xl3.w;
      zx = fmaxf(zx, 0.2f * zx); zy = fmaxf(zy, 0.2f * zy);
      zz = fmaxf(zz, 0.2f * zz); zw = fmaxf(zw, 0.2f * zw);
      p3 = att4.x * zx; p3 = fmaf(att4.y, zy, p3); p3 = fmaf(att4.z, zz, p3); p3 = fmaf(att4.w, zw, p3);
    }

#pragma unroll
    for (int off = 32; off > 0; off >>= 1) {
      p0 += __shfl_xor(p0, off, 64);
      p1 += __shfl_xor(p1, off, 64);
      p2 += __shfl_xor(p2, off, 64);
      p3 += __shfl_xor(p3, off, 64);
    }
    if (e + 1 >= re) p1 = -1e30f;
    if (e + 2 >= re) p2 = -1e30f;
    if (e + 3 >= re) p3 = -1e30f;

    const float bmx = fmaxf(fmaxf(p0, p1), fmaxf(p2, p3));
    const float nm = fmaxf(mrun, bmx);
    const float sc = exp2f(mrun - nm);
    const float w0 = exp2f(p0 - nm);
    const float w1 = exp2f(p1 - nm);
    const float w2 = exp2f(p2 - nm);
    const float w3 = exp2f(p3 - nm);
    den = fmaf(den, sc, (w0 + w1) + (w2 + w3));
    float tx = w0 * xl0.x; tx = fmaf(w1, xl1.x, tx); tx = fmaf(w2, xl2.x, tx); tx = fmaf(w3, xl3.x, tx);
    float ty = w0 * xl0.y; ty = fmaf(w1, xl1.y, ty); ty = fmaf(w2, xl2.y, ty); ty = fmaf(w3, xl3.y, ty);
    float tz = w0 * xl0.z; tz = fmaf(w1, xl1.z, tz); tz = fmaf(w2, xl2.z, tz); tz = fmaf(w3, xl3.z, tz);
    float tw = w0 * xl0.w; tw = fmaf(w1, xl1.w, tw); tw = fmaf(w2, xl2.w, tw); tw = fmaf(w3, xl3.w, tw);
    acc.x = fmaf(acc.x, sc, tx);
    acc.y = fmaf(acc.y, sc, ty);
    acc.z = fmaf(acc.z, sc, tz);
    acc.w = fmaf(acc.w, sc, tw);
    mrun = nm;
  }

  const float inv = (den > 0.f) ? __frcp_rn(den) : 0.f;
  const float4 bc4 = *(const float4*)(bconv + h4);
  const float4 g4 = *(const float4*)(gamma + h4);
  const float4 b4 = *(const float4*)(beta + h4);
  const float4 m4 = *(const float4*)(mean + h4);
  const float4 v4 = *(const float4*)(var + h4);
  float o[4] = {acc.x, acc.y, acc.z, acc.w};
  const float bc[4] = {bc4.x, bc4.y, bc4.z, bc4.w};
  const float gm[4] = {g4.x, g4.y, g4.z, g4.w};
  const float bt[4] = {b4.x, b4.y, b4.z, b4.w};
  const float mn[4] = {m4.x, m4.y, m4.z, m4.w};
  const float vr[4] = {v4.x, v4.y, v4.z, v4.w};
  float res[4];
#pragma unroll
  for (int j = 0; j < 4; ++j) {
    float y = fmaf(o[j], inv, bc[j]);
    y = (y - mn[j]) * rsqrtf(vr[j] + 1e-5f) * gm[j] + bt[j];
    res[j] = relu_last ? fmaxf(y, 0.f) : fmaxf(y, 0.01f * y);
  }
  ushort4 rb;
  rb.x = f2bf(res[0]); rb.y = f2bf(res[1]); rb.z = f2bf(res[2]); rb.w = f2bf(res[3]);
  *(ushort4*)(hbf + (size_t)iu * HIDDEN + h4) = rb;
}

// ---------------- pooling + heads ----------------
__device__ __forceinline__ int lbound(const int* a, int n, int v) {
  int lo = 0, hi = n;
  while (lo < hi) { int m = (lo + hi) >> 1; if (a[m] < v) lo = m + 1; else hi = m; }
  return lo;
}

__global__ void pool_kernel(const unsigned short* __restrict__ h, const int* __restrict__ batch,
                            float* __restrict__ g) {
  const int gi = blockIdx.x;
  const int t = threadIdx.x;
  int s = lbound(batch, N_NODES, gi);
  int e = lbound(batch, N_NODES, gi + 1);
  float sum = 0.f;
  for (int i = s; i < e; ++i) sum += bf2f(h[(size_t)i * HIDDEN + t]);
  float c = (float)(e - s);
  g[gi * HIDDEN + t] = sum / fmaxf(c, 1.f);
}

__global__ void head_kernel(const float* __restrict__ g,
                            const float* __restrict__ w1, const float* __restrict__ b1,
                            const float* __restrict__ w2, const float* __restrict__ b2,
                            float* __restrict__ out) {
  int idx = blockIdx.x * 256 + threadIdx.x;
  if (idx >= N_GRAPHS * N_OUT * 2) return;
  int which = idx >> 9;
  int rem = idx & 511;
  int row = rem >> 3, col = rem & 7;
  const float* w = which ? w2 : w1;
  float s = which ? b2[col] : b1[col];
  for (int k = 0; k < HIDDEN; ++k) s = fmaf(g[row * HIDDEN + k], w[k * N_OUT + col], s);
  out[idx] = s;
}

extern "C" void kernel_launch(void* const* d_in, const int* in_sizes, int n_in,
                              void* d_out, int out_size, void* d_ws, size_t ws_size,
                              hipStream_t stream) {
  const float* x     = (const float*)d_in[0];
  const int*   ei    = (const int*)d_in[1];
  const float* eattr = (const float*)d_in[2];
  const int*   batch = (const int*)d_in[3];
  const float* Wl1   = (const float*)d_in[4];
  const float* Wr1   = (const float*)d_in[5];
  const float* We1   = (const float*)d_in[6];
  const float* bl1   = (const float*)d_in[7];
  const float* br1   = (const float*)d_in[8];
  const float* att1  = (const float*)d_in[9];
  const float* b1    = (const float*)d_in[10];
  const float* Wls   = (const float*)d_in[11];
  const float* Wrs   = (const float*)d_in[12];
  const float* Wes   = (const float*)d_in[13];
  const float* bls   = (const float*)d_in[14];
  const float* brs   = (const float*)d_in[15];
  const float* atts  = (const float*)d_in[16];
  const float* bs    = (const float*)d_in[17];
  const float* bng   = (const float*)d_in[18];
  const float* bnb   = (const float*)d_in[19];
  const float* bnm   = (const float*)d_in[20];
  const float* bnv   = (const float*)d_in[21];
  const float* l1w   = (const float*)d_in[22];
  const float* l1b   = (const float*)d_in[23];
  const float* l2w   = (const float*)d_in[24];
  const float* l2b   = (const float*)d_in[25];
  float* out = (float*)d_out;

  char* ws = (char*)d_ws;
  auto alloc = [&](size_t bytes) {
    char* p = ws;
    ws += (bytes + 255) & ~(size_t)255;
    return p;
  };
  int*   counts   = (int*)alloc((size_t)N_NODES * 4);
  int*   offs     = (int*)alloc((size_t)(N_NODES + 1) * 4);
  int*   cursor   = (int*)alloc((size_t)N_NODES * 4);
  int*   csr_src  = (int*)alloc((size_t)N_EDGES * 4);
  unsigned int* attr16 = (unsigned int*)alloc((size_t)N_EDGES * 8 * 4);
  unsigned int* WePall = (unsigned int*)alloc((size_t)5 * 8 * 256 * 4);
  unsigned short* xlr  = (unsigned short*)alloc((size_t)N_NODES * 512 * 2);
  unsigned short* hbf0 = (unsigned short*)alloc((size_t)N_NODES * 256 * 2);
  unsigned short* hbf1 = (unsigned short*)alloc((size_t)N_NODES * 256 * 2);
  unsigned short* xbf  = (unsigned short*)alloc((size_t)N_NODES * NODE_DIM * 2);
  unsigned short* WTall = (unsigned short*)alloc((size_t)5 * 512 * 256 * 2);
  float* g        = (float*)alloc((size_t)N_GRAPHS * 256 * 4);
  int*   order    = (int*)alloc((size_t)N_NODES * 4);

  hipMemsetAsync(counts, 0, (size_t)N_NODES * 4, stream);
  hist_kernel<<<(N_EDGES + 255) / 256, 256, 0, stream>>>(ei + N_EDGES, counts, N_EDGES);
  scan_kernel<<<1, 256, 0, stream>>>(counts, offs, cursor, N_NODES);
  scatter_kernel<<<(N_EDGES + 255) / 256, 256, 0, stream>>>(ei, eattr, cursor, csr_src,
                                                            attr16, N_EDGES);
  degsort_kernel<<<1, 256, 0, stream>>>(offs, order, N_NODES);
  cvt_x<<<(N_NODES * NODE_DIM / 4 + 255) / 256, 256, 0, stream>>>(x, xbf,
                                                                  N_NODES * NODE_DIM / 4);
  {
    dim3 wgrid(512, 5);
    cvt_w_all<<<wgrid, 256, 0, stream>>>(Wl1, Wr1, Wls, Wrs, WTall);
  }
  cvt_wep<<<(5 * 8 * 256 + 255) / 256, 256, 0, stream>>>(We1, Wes, WePall);

  for (int layer = 0; layer < 5; ++layer) {
    int K = (layer == 0) ? NODE_DIM : HIDDEN;
    const float* bl = (layer == 0) ? bl1 : bls + (layer - 1) * HIDDEN;
    const float* br = (layer == 0) ? br1 : brs + (layer - 1) * HIDDEN;
    const float* at = (layer == 0) ? att1 : atts + (layer - 1) * HIDDEN;
    const float* bc = (layer == 0) ? b1 : bs + (layer - 1) * HIDDEN;
    const unsigned short* Abf = (layer == 0) ? xbf : ((layer & 1) ? hbf0 : hbf1);
    unsigned short* hbf_out = (layer & 1) ? hbf1 : hbf0;
    const unsigned short* WT = WTall + (size_t)layer * 512 * 256;
    const unsigned int* WeP = WePall + (size_t)layer * 8 * 256;

    dim3 ggrid((N_NODES + 63) / 64, 4);
    gemm_mfma<<<ggrid, 256, 0, stream>>>(Abf, WT, bl, br, xlr, N_NODES, K);
    edge_gat<<<N_NODES / 4, 256, 0, stream>>>(xlr, offs, csr_src, attr16, WeP, at, bc,
                                              bng + layer * HIDDEN, bnb + layer * HIDDEN,
                                              bnm + layer * HIDDEN, bnv + layer * HIDDEN,
                                              order, hbf_out, (layer == 4) ? 1 : 0);
  }
  // layer 4 (even) wrote hbf0
  pool_kernel<<<N_GRAPHS, 256, 0, stream>>>(hbf0, batch, g);
  head_kernel<<<4, 256, 0, stream>>>(g, l1w, l1b, l2w, l2b, out);
}

// Round 19
// 500.782 us; speedup vs baseline: 1.0110x; 1.0110x over previous
//
#include <hip/hip_runtime.h>

#define N_NODES 10000
#define N_EDGES 320000
#define NODE_DIM 128
#define EDGE_DIM 16
#define HIDDEN 256
#define N_OUT 8
#define N_GRAPHS 64
#define LOG2E 1.4426950408889634f

typedef float f32x4 __attribute__((ext_vector_type(4)));
typedef short bf16x8 __attribute__((ext_vector_type(8)));
typedef _Float16 half2_t __attribute__((ext_vector_type(2)));

__device__ __forceinline__ unsigned short f2bf(float f) {
  unsigned int u = __float_as_uint(f);
  unsigned int r = (u + 0x7fff + ((u >> 16) & 1)) >> 16;
  return (unsigned short)r;
}

__device__ __forceinline__ float bf2f(unsigned short u) {
  return __uint_as_float((unsigned int)u << 16);
}

__device__ __forceinline__ unsigned int packh2(float a, float b) {
  half2_t h;
  h.x = (_Float16)a;
  h.y = (_Float16)b;
  return __builtin_bit_cast(unsigned int, h);
}

// ---------------- CSR build ----------------
__global__ void hist_kernel(const int* __restrict__ dst, int* __restrict__ counts, int E) {
  int e = blockIdx.x * blockDim.x + threadIdx.x;
  if (e < E) atomicAdd(&counts[dst[e]], 1);
}

__global__ void scan_kernel(const int* __restrict__ counts, int* __restrict__ offs,
                            int* __restrict__ cursor, int n) {
  __shared__ int part[256];
  int t = threadIdx.x;
  const int chunk = (n + 255) / 256;
  int base = t * chunk;
  int s = 0;
  for (int j = 0; j < chunk; ++j) { int i = base + j; if (i < n) s += counts[i]; }
  part[t] = s;
  __syncthreads();
  for (int off = 1; off < 256; off <<= 1) {
    int v = (t >= off) ? part[t - off] : 0;
    __syncthreads();
    part[t] += v;
    __syncthreads();
  }
  int run = (t == 0) ? 0 : part[t - 1];
  for (int j = 0; j < chunk; ++j) {
    int i = base + j;
    if (i < n) { offs[i] = run; cursor[i] = run; run += counts[i]; }
  }
  if (t == 255) offs[n] = run;
}

// scatter edges into CSR order; attr packed as 8x half2 per edge
__global__ void scatter_kernel(const int* __restrict__ ei, const float* __restrict__ eattr,
                               int* __restrict__ cursor, int* __restrict__ csr_src,
                               unsigned int* __restrict__ attr16, int E) {
  int e = blockIdx.x * blockDim.x + threadIdx.x;
  if (e >= E) return;
  int s = ei[e];
  int d = ei[E + e];
  int slot = atomicAdd(&cursor[d], 1);
  csr_src[slot] = s;
  const float4* in = (const float4*)(eattr + (size_t)e * 16);
  float4 v0 = in[0], v1 = in[1], v2 = in[2], v3 = in[3];
  uint4 o0, o1;
  o0.x = packh2(v0.x, v0.y); o0.y = packh2(v0.z, v0.w);
  o0.z = packh2(v1.x, v1.y); o0.w = packh2(v1.z, v1.w);
  o1.x = packh2(v2.x, v2.y); o1.y = packh2(v2.z, v2.w);
  o1.z = packh2(v3.x, v3.y); o1.w = packh2(v3.z, v3.w);
  uint4* outp = (uint4*)(attr16 + (size_t)slot * 8);
  outp[0] = o0; outp[1] = o1;
}

// ---------------- degree sort, single block, LDS histogram + cursors ----------------
__global__ __launch_bounds__(256) void degsort_kernel(const int* __restrict__ offs,
                                                      int* __restrict__ order, int n) {
  __shared__ int bins[512];
  __shared__ int curs[512];
  const int t = threadIdx.x;
  bins[t] = 0;
  bins[t + 256] = 0;
  __syncthreads();
  for (int i = t; i < n; i += 256) {
    int d = offs[i + 1] - offs[i];
    if (d > 511) d = 511;
    atomicAdd(&bins[d], 1);
  }
  __syncthreads();
  if (t == 0) {
    int run = 0;
    for (int d = 511; d >= 0; --d) { curs[d] = run; run += bins[d]; }
  }
  __syncthreads();
  for (int i = t; i < n; i += 256) {
    int d = offs[i + 1] - offs[i];
    if (d > 511) d = 511;
    int pos = atomicAdd(&curs[d], 1);
    order[pos] = i;
  }
}

// ---------------- weight / activation conversion (all layers upfront) ----------------
__global__ void cvt_w_all(const float* __restrict__ Wl1, const float* __restrict__ Wr1,
                          const float* __restrict__ Wls, const float* __restrict__ Wrs,
                          unsigned short* __restrict__ WTall) {
  const int layer = blockIdx.y;
  const int K = (layer == 0) ? NODE_DIM : HIDDEN;
  int idx = blockIdx.x * 256 + threadIdx.x;
  if (idx >= 512 * K) return;
  int n = idx / K, k = idx - n * K;
  const float* Wl = (layer == 0) ? Wl1 : Wls + (size_t)(layer - 1) * HIDDEN * HIDDEN;
  const float* Wr = (layer == 0) ? Wr1 : Wrs + (size_t)(layer - 1) * HIDDEN * HIDDEN;
  float v = (n < 256) ? Wl[(size_t)k * 256 + n] : Wr[(size_t)k * 256 + (n - 256)];
  WTall[(size_t)layer * 512 * 256 + idx] = f2bf(v);
}

// WeP[layer][dp][col] = pack(We[2dp][col], We[2dp+1][col]) as half2
__global__ void cvt_wep(const float* __restrict__ We1, const float* __restrict__ Wes,
                        unsigned int* __restrict__ WePall) {
  int idx = blockIdx.x * 256 + threadIdx.x;
  if (idx >= 5 * 8 * 256) return;
  int layer = idx >> 11;
  int rem = idx & 2047;
  int dp = rem >> 8, col = rem & 255;
  const float* W = (layer == 0) ? We1 : Wes + (size_t)(layer - 1) * EDGE_DIM * HIDDEN;
  WePall[idx] = packh2(W[(2 * dp) * HIDDEN + col], W[(2 * dp + 1) * HIDDEN + col]);
}

__global__ void cvt_x(const float* __restrict__ X, unsigned short* __restrict__ XB, int total4) {
  int idx = blockIdx.x * 256 + threadIdx.x;
  if (idx >= total4) return;
  float4 v = *(const float4*)(X + (size_t)idx * 4);
  ushort4 o;
  o.x = f2bf(v.x); o.y = f2bf(v.y); o.z = f2bf(v.z); o.w = f2bf(v.w);
  *(ushort4*)(XB + (size_t)idx * 4) = o;
}

// ---------------- MFMA node GEMM: 64-row tile (32KB LDS), swizzled A, bf16 output ----------------
__global__ __launch_bounds__(256) void gemm_mfma(
    const unsigned short* __restrict__ A,   // [M][K] bf16 row-major
    const unsigned short* __restrict__ WT,  // [512][K] bf16 (output-col major)
    const float* __restrict__ bl, const float* __restrict__ br,
    unsigned short* __restrict__ C, int M, int K) {
  __shared__ unsigned short Atile[64 * 256];  // 32KB
  const int t = threadIdx.x;
  const int wv = t >> 6;
  const int l = t & 63;
  const int bm = blockIdx.x * 64;
  const int bn = blockIdx.y * 128;
  const int CPR = K >> 3;
  const int nchunks = 64 * CPR;

  for (int p = t; p < nchunks; p += 256) {
    const int r = p / CPR;
    const int c = p - r * CPR;
    int gr = bm + r; if (gr >= M) gr = M - 1;
    const uint4 v = *(const uint4*)(A + (size_t)gr * K + c * 8);
    const int eff = c ^ (r & 7);
    *(uint4*)((char*)Atile + ((size_t)r * CPR + eff) * 16) = v;
  }
  __syncthreads();

  const int col0 = bn + wv * 32 + (l & 15);
  const int col1 = col0 + 16;
  const int kg = l >> 4;
  f32x4 acc[4][2];
#pragma unroll
  for (int mt = 0; mt < 4; ++mt) {
    acc[mt][0] = (f32x4){0.f, 0.f, 0.f, 0.f};
    acc[mt][1] = (f32x4){0.f, 0.f, 0.f, 0.f};
  }
  const int steps = K >> 5;
  for (int ks = 0; ks < steps; ++ks) {
    const bf16x8 bf0 = *(const bf16x8*)(WT + (size_t)col0 * K + ks * 32 + kg * 8);
    const bf16x8 bf1 = *(const bf16x8*)(WT + (size_t)col1 * K + ks * 32 + kg * 8);
#pragma unroll
    for (int mt = 0; mt < 4; ++mt) {
      const int row = mt * 16 + (l & 15);
      const int eff = (ks * 4 + kg) ^ (row & 7);
      const bf16x8 af = *(const bf16x8*)((const char*)Atile + ((size_t)row * CPR + eff) * 16);
      acc[mt][0] = __builtin_amdgcn_mfma_f32_16x16x32_bf16(af, bf0, acc[mt][0], 0, 0, 0);
      acc[mt][1] = __builtin_amdgcn_mfma_f32_16x16x32_bf16(af, bf1, acc[mt][1], 0, 0, 0);
    }
  }
  const float bias0 = (col0 < 256) ? bl[col0] : br[col0 - 256];
  const float bias1 = (col1 < 256) ? bl[col1] : br[col1 - 256];
#pragma unroll
  for (int mt = 0; mt < 4; ++mt) {
#pragma unroll
    for (int j = 0; j < 4; ++j) {
      int row = bm + mt * 16 + (l >> 4) * 4 + j;
      if (row < M) {
        C[(size_t)row * 512 + col0] = f2bf(acc[mt][0][j] + bias0);
        C[(size_t)row * 512 + col1] = f2bf(acc[mt][1][j] + bias1);
      }
    }
  }
}

// ---------------- fused edge scoring + segment softmax + aggregate + BN + act ----------------
// Final converged structure: fdot2, bf16 xlr, 4-edge batch, shfl reduce,
// launch_bounds(256,4), degree-sorted node order, bf16 output.
__global__ __launch_bounds__(256, 4) void edge_gat(
    const unsigned short* __restrict__ xlr,
    const int* __restrict__ offs, const int* __restrict__ csr_src,
    const unsigned int* __restrict__ attr16,
    const unsigned int* __restrict__ WeP, const float* __restrict__ att,
    const float* __restrict__ bconv,
    const float* __restrict__ gamma, const float* __restrict__ beta,
    const float* __restrict__ mean, const float* __restrict__ var,
    const int* __restrict__ order,
    unsigned short* __restrict__ hbf, int relu_last) {
  const int t = threadIdx.x;
  const int w = t >> 6;
  const int l = t & 63;
  const int h4 = l << 2;
  const int iu = __builtin_amdgcn_readfirstlane(order[blockIdx.x * 4 + w]);

  float4 att4 = *(const float4*)(att + h4);
  att4.x *= LOG2E; att4.y *= LOG2E; att4.z *= LOG2E; att4.w *= LOG2E;
  const ushort4 xru = *(const ushort4*)(xlr + (size_t)iu * 512 + HIDDEN + h4);
  const float4 xr4 = {bf2f(xru.x), bf2f(xru.y), bf2f(xru.z), bf2f(xru.w)};

  const int rs = __builtin_amdgcn_readfirstlane(offs[iu]);
  const int re = __builtin_amdgcn_readfirstlane(offs[iu + 1]);

  float mrun = -1e30f, den = 0.f;
  float4 acc = make_float4(0.f, 0.f, 0.f, 0.f);

  for (int e = rs; e < re; e += 4) {
    const int e0 = e;
    const int e1 = (e + 1 < re) ? e + 1 : e;
    const int e2 = (e + 2 < re) ? e + 2 : e;
    const int e3 = (e + 3 < re) ? e + 3 : e;
    const int s0 = __builtin_amdgcn_readfirstlane(csr_src[e0]);
    const int s1 = __builtin_amdgcn_readfirstlane(csr_src[e1]);
    const int s2 = __builtin_amdgcn_readfirstlane(csr_src[e2]);
    const int s3 = __builtin_amdgcn_readfirstlane(csr_src[e3]);
    const ushort4 xu0 = *(const ushort4*)(xlr + (size_t)s0 * 512 + h4);
    const ushort4 xu1 = *(const ushort4*)(xlr + (size_t)s1 * 512 + h4);
    const ushort4 xu2 = *(const ushort4*)(xlr + (size_t)s2 * 512 + h4);
    const ushort4 xu3 = *(const ushort4*)(xlr + (size_t)s3 * 512 + h4);
    const float4 xl0 = {bf2f(xu0.x), bf2f(xu0.y), bf2f(xu0.z), bf2f(xu0.w)};
    const float4 xl1 = {bf2f(xu1.x), bf2f(xu1.y), bf2f(xu1.z), bf2f(xu1.w)};
    const float4 xl2 = {bf2f(xu2.x), bf2f(xu2.y), bf2f(xu2.z), bf2f(xu2.w)};
    const float4 xl3 = {bf2f(xu3.x), bf2f(xu3.y), bf2f(xu3.z), bf2f(xu3.w)};

    float z0x = xr4.x, z0y = xr4.y, z0z = xr4.z, z0w = xr4.w;
    float z1x = xr4.x, z1y = xr4.y, z1z = xr4.z, z1w = xr4.w;
    float z2x = xr4.x, z2y = xr4.y, z2z = xr4.z, z2w = xr4.w;
    float z3x = xr4.x, z3y = xr4.y, z3z = xr4.z, z3w = xr4.w;

#pragma unroll
    for (int dp = 0; dp < 8; ++dp) {
      const uint4 wb = *(const uint4*)(WeP + dp * HIDDEN + h4);
      const half2_t wx = __builtin_bit_cast(half2_t, wb.x);
      const half2_t wy = __builtin_bit_cast(half2_t, wb.y);
      const half2_t wz = __builtin_bit_cast(half2_t, wb.z);
      const half2_t ww = __builtin_bit_cast(half2_t, wb.w);
      const half2_t a0 = __builtin_bit_cast(half2_t, attr16[(size_t)e0 * 8 + dp]);
      const half2_t a1 = __builtin_bit_cast(half2_t, attr16[(size_t)e1 * 8 + dp]);
      const half2_t a2 = __builtin_bit_cast(half2_t, attr16[(size_t)e2 * 8 + dp]);
      const half2_t a3 = __builtin_bit_cast(half2_t, attr16[(size_t)e3 * 8 + dp]);
      z0x = __builtin_amdgcn_fdot2(a0, wx, z0x, false);
      z0y = __builtin_amdgcn_fdot2(a0, wy, z0y, false);
      z0z = __builtin_amdgcn_fdot2(a0, wz, z0z, false);
      z0w = __builtin_amdgcn_fdot2(a0, ww, z0w, false);
      z1x = __builtin_amdgcn_fdot2(a1, wx, z1x, false);
      z1y = __builtin_amdgcn_fdot2(a1, wy, z1y, false);
      z1z = __builtin_amdgcn_fdot2(a1, wz, z1z, false);
      z1w = __builtin_amdgcn_fdot2(a1, ww, z1w, false);
      z2x = __builtin_amdgcn_fdot2(a2, wx, z2x, false);
      z2y = __builtin_amdgcn_fdot2(a2, wy, z2y, false);
      z2z = __builtin_amdgcn_fdot2(a2, wz, z2z, false);
      z2w = __builtin_amdgcn_fdot2(a2, ww, z2w, false);
      z3x = __builtin_amdgcn_fdot2(a3, wx, z3x, false);
      z3y = __builtin_amdgcn_fdot2(a3, wy, z3y, false);
      z3z = __builtin_amdgcn_fdot2(a3, wz, z3z, false);
      z3w = __builtin_amdgcn_fdot2(a3, ww, z3w, false);
    }

    float p0, p1, p2, p3;
    {
      float zx, zy, zz, zw;
      zx = z0x + xl0.x; zy = z0y + xl0.y; zz = z0z + xl0.z; zw = z0w + xl0.w;
      zx = fmaxf(zx, 0.2f * zx); zy = fmaxf(zy, 0.2f * zy);
      zz = fmaxf(zz, 0.2f * zz); zw = fmaxf(zw, 0.2f * zw);
      p0 = att4.x * zx; p0 = fmaf(att4.y, zy, p0); p0 = fmaf(att4.z, zz, p0); p0 = fmaf(att4.w, zw, p0);
      zx = z1x + xl1.x; zy = z1y + xl1.y; zz = z1z + xl1.z; zw = z1w + xl1.w;
      zx = fmaxf(zx, 0.2f * zx); zy = fmaxf(zy, 0.2f * zy);
      zz = fmaxf(zz, 0.2f * zz); zw = fmaxf(zw, 0.2f * zw);
      p1 = att4.x * zx; p1 = fmaf(att4.y, zy, p1); p1 = fmaf(att4.z, zz, p1); p1 = fmaf(att4.w, zw, p1);
      zx = z2x + xl2.x; zy = z2y + xl2.y; zz = z2z + xl2.z; zw = z2w + xl2.w;
      zx = fmaxf(zx, 0.2f * zx); zy = fmaxf(zy, 0.2f * zy);
      zz = fmaxf(zz, 0.2f * zz); zw = fmaxf(zw, 0.2f * zw);
      p2 = att4.x * zx; p2 = fmaf(att4.y, zy, p2); p2 = fmaf(att4.z, zz, p2); p2 = fmaf(att4.w, zw, p2);
      zx = z3x + xl3.x; zy = z3y + xl3.y; zz = z3z + xl3.z; zw = z3w + xl3.w;
      zx = fmaxf(zx, 0.2f * zx); zy = fmaxf(zy, 0.2f * zy);
      zz = fmaxf(zz, 0.2f * zz); zw = fmaxf(zw, 0.2f * zw);
      p3 = att4.x * zx; p3 = fmaf(att4.y, zy, p3); p3 = fmaf(att4.z, zz, p3); p3 = fmaf(att4.w, zw, p3);
    }

#pragma unroll
    for (int off = 32; off > 0; off >>= 1) {
      p0 += __shfl_xor(p0, off, 64);
      p1 += __shfl_xor(p1, off, 64);
      p2 += __shfl_xor(p2, off, 64);
      p3 += __shfl_xor(p3, off, 64);
    }
    if (e + 1 >= re) p1 = -1e30f;
    if (e + 2 >= re) p2 = -1e30f;
    if (e + 3 >= re) p3 = -1e30f;

    const float bmx = fmaxf(fmaxf(p0, p1), fmaxf(p2, p3));
    const float nm = fmaxf(mrun, bmx);
    const float sc = exp2f(mrun - nm);
    const float w0 = exp2f(p0 - nm);
    const float w1 = exp2f(p1 - nm);
    const float w2 = exp2f(p2 - nm);
    const float w3 = exp2f(p3 - nm);
    den = fmaf(den, sc, (w0 + w1) + (w2 + w3));
    float tx = w0 * xl0.x; tx = fmaf(w1, xl1.x, tx); tx = fmaf(w2, xl2.x, tx); tx = fmaf(w3, xl3.x, tx);
    float ty = w0 * xl0.y; ty = fmaf(w1, xl1.y, ty); ty = fmaf(w2, xl2.y, ty); ty = fmaf(w3, xl3.y, ty);
    float tz = w0 * xl0.z; tz = fmaf(w1, xl1.z, tz); tz = fmaf(w2, xl2.z, tz); tz = fmaf(w3, xl3.z, tz);
    float tw = w0 * xl0.w; tw = fmaf(w1, xl1.w, tw); tw = fmaf(w2, xl2.w, tw); tw = fmaf(w3, xl3.w, tw);
    acc.x = fmaf(acc.x, sc, tx);
    acc.y = fmaf(acc.y, sc, ty);
    acc.z = fmaf(acc.z, sc, tz);
    acc.w = fmaf(acc.w, sc, tw);
    mrun = nm;
  }

  const float inv = (den > 0.f) ? __frcp_rn(den) : 0.f;
  const float4 bc4 = *(const float4*)(bconv + h4);
  const float4 g4 = *(const float4*)(gamma + h4);
  const float4 b4 = *(const float4*)(beta + h4);
  const float4 m4 = *(const float4*)(mean + h4);
  const float4 v4 = *(const float4*)(var + h4);
  float o[4] = {acc.x, acc.y, acc.z, acc.w};
  const float bc[4] = {bc4.x, bc4.y, bc4.z, bc4.w};
  const float gm[4] = {g4.x, g4.y, g4.z, g4.w};
  const float bt[4] = {b4.x, b4.y, b4.z, b4.w};
  const float mn[4] = {m4.x, m4.y, m4.z, m4.w};
  const float vr[4] = {v4.x, v4.y, v4.z, v4.w};
  float res[4];
#pragma unroll
  for (int j = 0; j < 4; ++j) {
    float y = fmaf(o[j], inv, bc[j]);
    y = (y - mn[j]) * rsqrtf(vr[j] + 1e-5f) * gm[j] + bt[j];
    res[j] = relu_last ? fmaxf(y, 0.f) : fmaxf(y, 0.01f * y);
  }
  ushort4 rb;
  rb.x = f2bf(res[0]); rb.y = f2bf(res[1]); rb.z = f2bf(res[2]); rb.w = f2bf(res[3]);
  *(ushort4*)(hbf + (size_t)iu * HIDDEN + h4) = rb;
}

// ---------------- pooling + heads ----------------
__device__ __forceinline__ int lbound(const int* a, int n, int v) {
  int lo = 0, hi = n;
  while (lo < hi) { int m = (lo + hi) >> 1; if (a[m] < v) lo = m + 1; else hi = m; }
  return lo;
}

__global__ void pool_kernel(const unsigned short* __restrict__ h, const int* __restrict__ batch,
                            float* __restrict__ g) {
  const int gi = blockIdx.x;
  const int t = threadIdx.x;
  int s = lbound(batch, N_NODES, gi);
  int e = lbound(batch, N_NODES, gi + 1);
  float sum = 0.f;
  for (int i = s; i < e; ++i) sum += bf2f(h[(size_t)i * HIDDEN + t]);
  float c = (float)(e - s);
  g[gi * HIDDEN + t] = sum / fmaxf(c, 1.f);
}

__global__ void head_kernel(const float* __restrict__ g,
                            const float* __restrict__ w1, const float* __restrict__ b1,
                            const float* __restrict__ w2, const float* __restrict__ b2,
                            float* __restrict__ out) {
  int idx = blockIdx.x * 256 + threadIdx.x;
  if (idx >= N_GRAPHS * N_OUT * 2) return;
  int which = idx >> 9;
  int rem = idx & 511;
  int row = rem >> 3, col = rem & 7;
  const float* w = which ? w2 : w1;
  float s = which ? b2[col] : b1[col];
  for (int k = 0; k < HIDDEN; ++k) s = fmaf(g[row * HIDDEN + k], w[k * N_OUT + col], s);
  out[idx] = s;
}

extern "C" void kernel_launch(void* const* d_in, const int* in_sizes, int n_in,
                              void* d_out, int out_size, void* d_ws, size_t ws_size,
                              hipStream_t stream) {
  const float* x     = (const float*)d_in[0];
  const int*   ei    = (const int*)d_in[1];
  const float* eattr = (const float*)d_in[2];
  const int*   batch = (const int*)d_in[3];
  const float* Wl1   = (const float*)d_in[4];
  const float* Wr1   = (const float*)d_in[5];
  const float* We1   = (const float*)d_in[6];
  const float* bl1   = (const float*)d_in[7];
  const float* br1   = (const float*)d_in[8];
  const float* att1  = (const float*)d_in[9];
  const float* b1    = (const float*)d_in[10];
  const float* Wls   = (const float*)d_in[11];
  const float* Wrs   = (const float*)d_in[12];
  const float* Wes   = (const float*)d_in[13];
  const float* bls   = (const float*)d_in[14];
  const float* brs   = (const float*)d_in[15];
  const float* atts  = (const float*)d_in[16];
  const float* bs    = (const float*)d_in[17];
  const float* bng   = (const float*)d_in[18];
  const float* bnb   = (const float*)d_in[19];
  const float* bnm   = (const float*)d_in[20];
  const float* bnv   = (const float*)d_in[21];
  const float* l1w   = (const float*)d_in[22];
  const float* l1b   = (const float*)d_in[23];
  const float* l2w   = (const float*)d_in[24];
  const float* l2b   = (const float*)d_in[25];
  float* out = (float*)d_out;

  char* ws = (char*)d_ws;
  auto alloc = [&](size_t bytes) {
    char* p = ws;
    ws += (bytes + 255) & ~(size_t)255;
    return p;
  };
  int*   counts   = (int*)alloc((size_t)N_NODES * 4);
  int*   offs     = (int*)alloc((size_t)(N_NODES + 1) * 4);
  int*   cursor   = (int*)alloc((size_t)N_NODES * 4);
  int*   csr_src  = (int*)alloc((size_t)N_EDGES * 4);
  unsigned int* attr16 = (unsigned int*)alloc((size_t)N_EDGES * 8 * 4);
  unsigned int* WePall = (unsigned int*)alloc((size_t)5 * 8 * 256 * 4);
  unsigned short* xlr  = (unsigned short*)alloc((size_t)N_NODES * 512 * 2);
  unsigned short* hbf0 = (unsigned short*)alloc((size_t)N_NODES * 256 * 2);
  unsigned short* hbf1 = (unsigned short*)alloc((size_t)N_NODES * 256 * 2);
  unsigned short* xbf  = (unsigned short*)alloc((size_t)N_NODES * NODE_DIM * 2);
  unsigned short* WTall = (unsigned short*)alloc((size_t)5 * 512 * 256 * 2);
  float* g        = (float*)alloc((size_t)N_GRAPHS * 256 * 4);
  int*   order    = (int*)alloc((size_t)N_NODES * 4);

  hipMemsetAsync(counts, 0, (size_t)N_NODES * 4, stream);
  hist_kernel<<<(N_EDGES + 255) / 256, 256, 0, stream>>>(ei + N_EDGES, counts, N_EDGES);
  scan_kernel<<<1, 256, 0, stream>>>(counts, offs, cursor, N_NODES);
  scatter_kernel<<<(N_EDGES + 255) / 256, 256, 0, stream>>>(ei, eattr, cursor, csr_src,
                                                            attr16, N_EDGES);
  degsort_kernel<<<1, 256, 0, stream>>>(offs, order, N_NODES);
  cvt_x<<<(N_NODES * NODE_DIM / 4 + 255) / 256, 256, 0, stream>>>(x, xbf,
                                                                  N_NODES * NODE_DIM / 4);
  {
    dim3 wgrid(512, 5);
    cvt_w_all<<<wgrid, 256, 0, stream>>>(Wl1, Wr1, Wls, Wrs, WTall);
  }
  cvt_wep<<<(5 * 8 * 256 + 255) / 256, 256, 0, stream>>>(We1, Wes, WePall);

  for (int layer = 0; layer < 5; ++layer) {
    int K = (layer == 0) ? NODE_DIM : HIDDEN;
    const float* bl = (layer == 0) ? bl1 : bls + (layer - 1) * HIDDEN;
    const float* br = (layer == 0) ? br1 : brs + (layer - 1) * HIDDEN;
    const float* at = (layer == 0) ? att1 : atts + (layer - 1) * HIDDEN;
    const float* bc = (layer == 0) ? b1 : bs + (layer - 1) * HIDDEN;
    const unsigned short* Abf = (layer == 0) ? xbf : ((layer & 1) ? hbf0 : hbf1);
    unsigned short* hbf_out = (layer & 1) ? hbf1 : hbf0;
    const unsigned short* WT = WTall + (size_t)layer * 512 * 256;
    const unsigned int* WeP = WePall + (size_t)layer * 8 * 256;

    dim3 ggrid((N_NODES + 63) / 64, 4);
    gemm_mfma<<<ggrid, 256, 0, stream>>>(Abf, WT, bl, br, xlr, N_NODES, K);
    edge_gat<<<N_NODES / 4, 256, 0, stream>>>(xlr, offs, csr_src, attr16, WeP, at, bc,
                                              bng + layer * HIDDEN, bnb + layer * HIDDEN,
                                              bnm + layer * HIDDEN, bnv + layer * HIDDEN,
                                              order, hbf_out, (layer == 4) ? 1 : 0);
  }
  // layer 4 (even) wrote hbf0
  pool_kernel<<<N_GRAPHS, 256, 0, stream>>>(hbf0, batch, g);
  head_kernel<<<4, 256, 0, stream>>>(g, l1w, l1b, l2w, l2b, out);
}